// Round 4
// baseline (676.017 us; speedup 1.0000x reference)
//
#include <hip/hip_runtime.h>

typedef __bf16 bf16_t;
typedef __bf16 bf16x8 __attribute__((ext_vector_type(8)));
typedef float f32x4 __attribute__((ext_vector_type(4)));

static constexpr int Bq = 4, Gg = 8, Nn = 128, Tt = 6000, Hh = 384;
static constexpr int TB = 12;             // t-values per tile
static constexpr int MR = TB * Gg;        // 96 rows per tile (row = tl*8 + g)
static constexpr int NTPB = Tt / TB;      // 500 tiles per batch
static constexpr int NTILES = Bq * NTPB;  // 2000 tiles
static constexpr int NIT = 8;             // tiles per persistent block
static constexpr int NBLK1 = NTILES / NIT;// 250 blocks
static constexpr int LDA = 136;           // As row stride (272B = 17*16 -> b128 aligned)
static constexpr int LDG = 392;           // Gi row stride (784B = 49*16)
static constexpr int LDSM = 392;          // Sm/Mm row stride
static constexpr int LDV = 132;           // Vv row stride (f32)
static constexpr int AS_ELEMS = MR * LDA; // 13056

// workspace layout (bytes)
static constexpr size_t OFF_WI  = 0;                                   // 384x128 bf16
static constexpr size_t OFF_WM  = OFF_WI + (size_t)Hh * Nn * 2;        // 384x384 bf16
static constexpr size_t OFF_WO  = OFF_WM + (size_t)Hh * Hh * 2;        // 128x768 bf16
static constexpr size_t OFF_PT  = OFF_WO + (size_t)Nn * 2 * Hh * 2;    // part[2000][16] f32
static constexpr size_t OFF_MRS = OFF_PT + (size_t)NTILES * 16 * 4;    // 32x2 f32
static constexpr size_t OFF_GO  = (size_t)1 << 20;                     // B*T*G*N bf16
static constexpr size_t WS_NEED = OFF_GO + (size_t)Bq * Tt * Gg * Nn * 2;

// k1 dynamic-LDS offsets (bytes)
static constexpr int SM_AS  = 0;        // As double buffer: 2 x [96][136] bf16 = 52224
static constexpr int SM_GI  = 52224;    // Gi [96][392] bf16 = 75264 -> 127488
static constexpr int SM_SM  = 127488;   // Sm [16][392] bf16 = 12544 -> 140032 (rows 12-15 zeroed)
static constexpr int SM_MM  = 140032;   // Mm [16][392] bf16 = 12544 -> 152576 (rows 12-15 zeroed)
static constexpr int SM_VV  = 152576;   // Vv [12][132] f32  =  6336 -> 158912
static constexpr int SM_ST  = 158912;   // st [16] f32 -> 158976
static constexpr int SMEM_BYTES = 158976;  // <= 160 KB, 1 block/CU, 8 waves

#define MFMA16(a, b, c) __builtin_amdgcn_mfma_f32_16x16x32_bf16((a), (b), (c), 0, 0, 0)

__global__ void k0_prep(const float* __restrict__ Wi, const float* __restrict__ Wm,
                        const float* __restrict__ Wo,
                        bf16_t* __restrict__ WiB, bf16_t* __restrict__ WmB,
                        bf16_t* __restrict__ WoB) {
    int i = blockIdx.x * blockDim.x + threadIdx.x;
    const int n1 = Hh * Nn, n2 = Hh * Hh, n3 = Nn * 2 * Hh;
    for (int idx = i; idx < n1 + n2 + n3; idx += gridDim.x * blockDim.x) {
        if (idx < n1)            WiB[idx] = (bf16_t)Wi[idx];
        else if (idx < n1 + n2)  WmB[idx - n1] = (bf16_t)Wm[idx - n1];
        else                     WoB[idx - n1 - n2] = (bf16_t)Wo[idx - n1 - n2];
    }
}

// As column swizzle at 16B granularity: granule (c>>3) XOR'd with tl = (row>>3)&7.
// Spreads staging writes (lanes differing in tl) across 8 16B slots; applied on
// both write and read side.
__device__ __forceinline__ int as_col(int row, int c) {
    return ((((c >> 3) ^ ((row >> 3) & 7)) << 3) | (c & 7));
}

__global__ __launch_bounds__(512, 2)
void k1_fused(const float* __restrict__ x,
              const bf16_t* __restrict__ WiB, const float* __restrict__ bi, const float* __restrict__ aip,
              const bf16_t* __restrict__ WmB, const float* __restrict__ bm, const float* __restrict__ amp,
              const bf16_t* __restrict__ WoB, const float* __restrict__ bo, const float* __restrict__ aop,
              bf16_t* __restrict__ go, float* __restrict__ part) {
    extern __shared__ char smem[];
    bf16_t* As = (bf16_t*)(smem + SM_AS);
    bf16_t* Gi = (bf16_t*)(smem + SM_GI);
    bf16_t* Sm = (bf16_t*)(smem + SM_SM);
    bf16_t* Mm = (bf16_t*)(smem + SM_MM);
    float*  Vv = (float*)(smem + SM_VV);
    float*  st = (float*)(smem + SM_ST);

    const int tid  = threadIdx.x;
    const int lane = tid & 63;
    const int w    = tid >> 6;       // wave 0..7
    const int l15  = lane & 15;
    const int l4   = lane >> 4;      // 0..3
    const int mh   = w >> 2;         // m-half (48 rows) for GEMM1/4
    const int ws4  = w & 3;          // col slice for GEMM1/4
    const int p    = blockIdx.x;     // persistent block id, tiles p*NIT .. p*NIT+7

    // staging ownership: thread covers 2 (g,n) rows, 3 f32x4 quads each
    const int g0 = tid >> 7, n0 = tid & 127;          // gn = tid
    const int g1 = g0 + 4,   n1 = n0;                 // gn = tid + 512

    // ---- prologue: zero Sm/Mm pad rows (12..15) and st
    for (int idx = tid; idx < 4 * LDSM; idx += 512) {
        Sm[12 * LDSM + idx] = (bf16_t)0.f;
        Mm[12 * LDSM + idx] = (bf16_t)0.f;
    }
    if (tid < 16) st[tid] = 0.f;

    const float ai = aip[0], am = amp[0], ao = aop[0];

    // ---- prologue: stage tile p*NIT into As buffer 0
    {
        const int tile = p * NIT;
        const int b = tile / NTPB, t0 = (tile % NTPB) * TB;
        f32x4 xr[2][3];
        #pragma unroll
        for (int q = 0; q < 3; q++) {
            xr[0][q] = *(const f32x4*)&x[((size_t)((b * Gg + g0) * Nn + n0)) * Tt + t0 + 4 * q];
            xr[1][q] = *(const f32x4*)&x[((size_t)((b * Gg + g1) * Nn + n1)) * Tt + t0 + 4 * q];
        }
        #pragma unroll
        for (int h = 0; h < 2; h++) {
            int gg = h ? g1 : g0, nn = h ? n1 : n0;
            #pragma unroll
            for (int q = 0; q < 3; q++)
                #pragma unroll
                for (int e = 0; e < 4; e++) {
                    int row = (q * 4 + e) * Gg + gg;
                    As[row * LDA + as_col(row, nn)] = (bf16_t)xr[h][q][e];
                }
        }
    }
    __syncthreads();

    for (int it = 0; it < NIT; it++) {
        const int cur = it & 1;
        const int tile = p * NIT + it;
        const int b = tile / NTPB, t0 = (tile % NTPB) * TB;
        bf16_t* Ac = As + cur * AS_ELEMS;
        bf16_t* An = As + (cur ^ 1) * AS_ELEMS;
        const bool hasNext = (it + 1 < NIT);

        // ---- A. issue next tile's global loads early (land during G1..G3)
        f32x4 xr[2][3];
        if (hasNext) {
            const int tn = tile + 1;
            const int bn = tn / NTPB, t0n = (tn % NTPB) * TB;
            #pragma unroll
            for (int q = 0; q < 3; q++) {
                xr[0][q] = *(const f32x4*)&x[((size_t)((bn * Gg + g0) * Nn + n0)) * Tt + t0n + 4 * q];
                xr[1][q] = *(const f32x4*)&x[((size_t)((bn * Gg + g1) * Nn + n1)) * Tt + t0n + 4 * q];
            }
        }

        // ---- B. GEMM1: Gi[96][384] = prelu(As @ WiB^T + bi), K=128
        // wave = 48-row half (mh) x 96-col slice (ws4); in-register group mean -> Sm
        {
            const int cb = ws4 * 96;
            f32x4 acc[3][6];
            #pragma unroll
            for (int mt = 0; mt < 3; mt++)
                #pragma unroll
                for (int ni = 0; ni < 6; ni++) acc[mt][ni] = f32x4{0.f, 0.f, 0.f, 0.f};
            #pragma unroll
            for (int kk = 0; kk < 4; kk++) {
                const int k0 = kk * 32 + l4 * 8;
                bf16x8 a[3], bb[6];
                #pragma unroll
                for (int ni = 0; ni < 6; ni++)
                    bb[ni] = *(const bf16x8*)&WiB[(cb + ni * 16 + l15) * Nn + k0];
                #pragma unroll
                for (int mt = 0; mt < 3; mt++) {
                    int row = mh * 48 + mt * 16 + l15;
                    a[mt] = *(const bf16x8*)&Ac[row * LDA + as_col(row, k0)];
                }
                #pragma unroll
                for (int mt = 0; mt < 3; mt++)
                    #pragma unroll
                    for (int ni = 0; ni < 6; ni++)
                        acc[mt][ni] = MFMA16(a[mt], bb[ni], acc[mt][ni]);
            }
            #pragma unroll
            for (int ni = 0; ni < 6; ni++) {
                int col = cb + ni * 16 + l15;
                float bv = bi[col];
                #pragma unroll
                for (int mt = 0; mt < 3; mt++) {
                    float ms = 0.f;
                    #pragma unroll
                    for (int j = 0; j < 4; j++) {
                        int row = mh * 48 + mt * 16 + l4 * 4 + j;
                        float v = acc[mt][ni][j] + bv;
                        v = v >= 0.f ? v : ai * v;
                        Gi[row * LDG + col] = (bf16_t)v;
                        ms += v;
                    }
                    // sum over the other l4 of this tl: l4 0<->1 (g0-3 + g4-7), 2<->3
                    ms += __shfl_xor(ms, 16, 64);
                    if ((l4 & 1) == 0) {
                        int tl = ((mh * 48 + mt * 16) >> 3) + (l4 >> 1);
                        Sm[tl * LDSM + col] = (bf16_t)(0.125f * ms);
                    }
                }
            }
        }
        __syncthreads();   // Sm + Gi ready

        // ---- D. GEMM2: Mm[12][384] = prelu(Sm @ WmB^T + bm), K=384 (rows 12-15 of Sm are 0)
        {
            const int cb2 = w * 48;
            f32x4 acc2[3];
            #pragma unroll
            for (int ni = 0; ni < 3; ni++) acc2[ni] = f32x4{0.f, 0.f, 0.f, 0.f};
            #pragma unroll
            for (int kk = 0; kk < 12; kk++) {
                const int k0 = kk * 32 + l4 * 8;
                bf16x8 a = *(const bf16x8*)&Sm[l15 * LDSM + k0];
                #pragma unroll
                for (int ni = 0; ni < 3; ni++) {
                    bf16x8 bb = *(const bf16x8*)&WmB[(cb2 + ni * 16 + l15) * Hh + k0];
                    acc2[ni] = MFMA16(a, bb, acc2[ni]);
                }
            }
            if (l4 < 3) {
                #pragma unroll
                for (int ni = 0; ni < 3; ni++) {
                    int col = cb2 + ni * 16 + l15;
                    float bv = bm[col];
                    #pragma unroll
                    for (int j = 0; j < 4; j++) {
                        float v = acc2[ni][j] + bv;
                        v = v >= 0.f ? v : am * v;
                        Mm[(l4 * 4 + j) * LDSM + col] = (bf16_t)v;
                    }
                }
            }
        }
        __syncthreads();   // Mm ready

        // ---- F. GEMM3: Vv[12][128] = Mm @ Wo2^T, K=384 (rows 12-15 of Mm are 0)
        {
            const int nblk = w * 16;
            f32x4 acc3 = f32x4{0.f, 0.f, 0.f, 0.f};
            #pragma unroll
            for (int kk = 0; kk < 12; kk++) {
                const int k0 = kk * 32 + l4 * 8;
                bf16x8 a = *(const bf16x8*)&Mm[l15 * LDSM + k0];
                bf16x8 bb = *(const bf16x8*)&WoB[(nblk + l15) * 768 + 384 + k0];
                acc3 = MFMA16(a, bb, acc3);
            }
            if (l4 < 3) {
                #pragma unroll
                for (int j = 0; j < 4; j++) Vv[(l4 * 4 + j) * LDV + nblk + l15] = acc3[j];
            }
        }
        __syncthreads();   // Vv ready

        // ---- H. write staged next-tile x into the other As buffer
        //         (safe: An last read in G1 of it-1; loads have had G1..G3 to land)
        if (hasNext) {
            #pragma unroll
            for (int h = 0; h < 2; h++) {
                int gg = h ? g1 : g0, nn = h ? n1 : n0;
                #pragma unroll
                for (int q = 0; q < 3; q++)
                    #pragma unroll
                    for (int e = 0; e < 4; e++) {
                        int row = (q * 4 + e) * Gg + gg;
                        An[row * LDA + as_col(row, nn)] = (bf16_t)xr[h][q][e];
                    }
            }
        }

        // ---- I. GEMM4: go[96][128] = prelu(Gi @ Wo1^T + Vv + bo), K=384; LN partials
        {
            const int cb4 = ws4 * 32;
            f32x4 acc4[3][2];
            #pragma unroll
            for (int mt = 0; mt < 3; mt++)
                #pragma unroll
                for (int ni = 0; ni < 2; ni++) acc4[mt][ni] = f32x4{0.f, 0.f, 0.f, 0.f};
            #pragma unroll
            for (int kk = 0; kk < 12; kk++) {
                const int k0 = kk * 32 + l4 * 8;
                bf16x8 b0 = *(const bf16x8*)&WoB[(cb4 + l15) * 768 + k0];
                bf16x8 b1 = *(const bf16x8*)&WoB[(cb4 + 16 + l15) * 768 + k0];
                bf16x8 a[3];
                #pragma unroll
                for (int mt = 0; mt < 3; mt++)
                    a[mt] = *(const bf16x8*)&Gi[(mh * 48 + mt * 16 + l15) * LDG + k0];
                #pragma unroll
                for (int mt = 0; mt < 3; mt++) {
                    acc4[mt][0] = MFMA16(a[mt], b0, acc4[mt][0]);
                    acc4[mt][1] = MFMA16(a[mt], b1, acc4[mt][1]);
                }
            }
            float gsum[4] = {0.f, 0.f, 0.f, 0.f};
            float gss[4]  = {0.f, 0.f, 0.f, 0.f};
            #pragma unroll
            for (int ni = 0; ni < 2; ni++) {
                int col = cb4 + ni * 16 + l15;
                float bv = bo[col];
                #pragma unroll
                for (int mt = 0; mt < 3; mt++) {
                    #pragma unroll
                    for (int j = 0; j < 4; j++) {
                        int row = mh * 48 + mt * 16 + l4 * 4 + j;
                        int tl = row >> 3;
                        int g = row & 7;
                        float v = acc4[mt][ni][j] + Vv[tl * LDV + col] + bv;
                        v = v >= 0.f ? v : ao * v;
                        go[((size_t)((b * Tt + t0 + tl) * Gg + g)) * Nn + col] = (bf16_t)v;
                        gsum[j] += v;
                        gss[j] += v * v;
                    }
                }
            }
            #pragma unroll
            for (int j = 0; j < 4; j++) {
                float s = gsum[j], q = gss[j];
                #pragma unroll
                for (int off = 1; off < 16; off <<= 1) {
                    s += __shfl_xor(s, off, 64);
                    q += __shfl_xor(q, off, 64);
                }
                if (l15 == 0) {
                    int g = (l4 * 4 + j) & 7;
                    atomicAdd(&st[g * 2 + 0], s);
                    atomicAdd(&st[g * 2 + 1], q);
                }
            }
        }
        __syncthreads();   // An staged; st complete; Gi free for next iter

        // ---- K. flush per-tile stats and reset
        if (tid < 16) {
            part[(size_t)tile * 16 + tid] = st[tid];
            st[tid] = 0.f;
        }
    }
}

// reduce part[2000][16] -> mr[32][2] (mean, rstd per (b,g))
__global__ __launch_bounds__(1024)
void k_final(const float* __restrict__ part, float* __restrict__ mr) {
    __shared__ float red[64][17];
    const int tid = threadIdx.x;          // 0..1023
    const int key = tid & 63;             // key = b*16 + g*2 + c
    const int chunk = tid >> 6;           // 0..15
    const int bb = key >> 4;
    const int t0 = chunk * 32;
    const int cnt = min(32, NTPB - t0);
    float s = 0.f;
    for (int i = 0; i < cnt; i++)
        s += part[(size_t)(bb * NTPB + t0 + i) * 16 + (key & 15)];
    red[key][chunk] = s;
    __syncthreads();
    if (tid < 64) {
        float tot = 0.f;
        #pragma unroll
        for (int ch = 0; ch < 16; ch++) tot += red[tid][ch];
        red[tid][16] = tot;
    }
    __syncthreads();
    if (tid < 32) {
        int b2 = tid >> 3, g2 = tid & 7;
        float s0 = red[b2 * 16 + g2 * 2][16];
        float s1 = red[b2 * 16 + g2 * 2 + 1][16];
        const float cntf = (float)Nn * (float)Tt;  // 768000
        float mean = s0 / cntf;
        float var = s1 / cntf - mean * mean;
        mr[tid * 2] = mean;
        mr[tid * 2 + 1] = rsqrtf(var + 1e-8f);
    }
}

__global__ __launch_bounds__(256)
void k_apply(const float* __restrict__ x, const bf16_t* __restrict__ go,
             const float* __restrict__ mr, const float* __restrict__ gamma,
             const float* __restrict__ beta, float* __restrict__ out) {
    __shared__ float tr[32][65];
    int bid = blockIdx.x;
    const int tt = bid % 94; bid /= 94;
    const int nn = bid & 3;  bid >>= 2;
    const int g = bid & 7;
    const int b = bid >> 3;
    const int t0 = tt * 64, n0 = nn * 32;
    const int tid = threadIdx.x;
    const float mean = mr[(b * 8 + g) * 2], rstd = mr[(b * 8 + g) * 2 + 1];

    for (int idx = tid; idx < 2048; idx += 256) {
        int nl = idx & 31, tl = idx >> 5;
        int t = t0 + tl;
        float v = 0.f;
        if (t < Tt) v = (float)go[((size_t)((b * Tt + t) * Gg + g)) * Nn + n0 + nl];
        tr[nl][tl] = v;
    }
    __syncthreads();
    for (int idx = tid; idx < 2048; idx += 256) {
        int tl = idx & 63, nl = idx >> 6;
        int t = t0 + tl;
        if (t < Tt) {
            int n = n0 + nl;
            size_t a = ((size_t)((b * Gg + g) * Nn + n)) * Tt + t;
            out[a] = x[a] + gamma[n] * (tr[nl][tl] - mean) * rstd + beta[n];
        }
    }
}

extern "C" void kernel_launch(void* const* d_in, const int* in_sizes, int n_in,
                              void* d_out, int out_size, void* d_ws, size_t ws_size,
                              hipStream_t stream) {
    const float* x     = (const float*)d_in[0];
    const float* Wi    = (const float*)d_in[1];
    const float* bi    = (const float*)d_in[2];
    const float* ai    = (const float*)d_in[3];
    const float* Wm    = (const float*)d_in[4];
    const float* bm    = (const float*)d_in[5];
    const float* am    = (const float*)d_in[6];
    const float* Wo    = (const float*)d_in[7];
    const float* bo    = (const float*)d_in[8];
    const float* ao    = (const float*)d_in[9];
    const float* gamma = (const float*)d_in[10];
    const float* beta  = (const float*)d_in[11];
    float* out = (float*)d_out;
    char* ws = (char*)d_ws;

    if (ws_size < WS_NEED) return;  // ~50.3 MB scratch required

    bf16_t* WiB  = (bf16_t*)(ws + OFF_WI);
    bf16_t* WmB  = (bf16_t*)(ws + OFF_WM);
    bf16_t* WoB  = (bf16_t*)(ws + OFF_WO);
    float*  prt  = (float*)(ws + OFF_PT);
    float*  mrs  = (float*)(ws + OFF_MRS);
    bf16_t* goB  = (bf16_t*)(ws + OFF_GO);

    k0_prep<<<dim3(512), dim3(256), 0, stream>>>(Wi, Wm, Wo, WiB, WmB, WoB);
    k1_fused<<<dim3(NBLK1), dim3(512), SMEM_BYTES, stream>>>(
        x, WiB, bi, ai, WmB, bm, am, WoB, bo, ao, goB, prt);
    k_final<<<dim3(1), dim3(1024), 0, stream>>>(prt, mrs);
    k_apply<<<dim3(Bq * Gg * 4 * 94), dim3(256), 0, stream>>>(x, goB, mrs, gamma, beta, out);
}

// Round 5
// 506.216 us; speedup vs baseline: 1.3354x; 1.3354x over previous
//
#include <hip/hip_runtime.h>

typedef __bf16 bf16_t;
typedef __bf16 bf16x8 __attribute__((ext_vector_type(8)));
typedef float f32x4 __attribute__((ext_vector_type(4)));

static constexpr int Bq = 4, Gg = 8, Nn = 128, Tt = 6000, Hh = 384;
static constexpr int TB = 16;              // t-values per tile
static constexpr int NTPB = Tt / TB;       // 375 tiles per batch
static constexpr int NTILES = Bq * NTPB;   // 1500 tiles (128 rows each)
static constexpr int LDA = 136;            // As row stride (bf16)
static constexpr int LDMM = 392;           // Mm row stride (bf16): 196 words %32=4

// ---- split-mode workspace layout (bytes)
static constexpr size_t OFF_WI  = 0;                                   // 384x128 bf16
static constexpr size_t OFF_WM  = OFF_WI + (size_t)Hh * Nn * 2;        // 384x384 bf16
static constexpr size_t OFF_WO  = OFF_WM + (size_t)Hh * Hh * 2;        // 128x768 bf16
static constexpr size_t OFF_PT  = OFF_WO + (size_t)Nn * 2 * Hh * 2;    // part[6000][16] f32 (fb: stats)
static constexpr size_t OFF_MRS = OFF_PT + (size_t)NTILES * 4 * 16 * 4;// 32x2 f32
static constexpr size_t OFF_GM  = (size_t)1 << 20;                     // gm [24000][384] bf16
static constexpr size_t OFF_V   = OFF_GM + (size_t)Bq * Tt * Hh * 2;   // v  [24000][128] f32
static constexpr size_t OFF_GO  = OFF_V + (size_t)Bq * Tt * Nn * 4;    // go [192000][128] bf16
static constexpr size_t OFF_GI  = OFF_GO + (size_t)Bq * Tt * Gg * Nn * 2; // gi chunk
static constexpr size_t GI_BYTES_FULL = (size_t)NTILES * 128 * Hh * 2; // 147.5 MB
// fallback layout: go at 1MB (stats at OFF_PT)
static constexpr size_t OFF_GO_FB = (size_t)1 << 20;
static constexpr size_t WS_FB = OFF_GO_FB + (size_t)Bq * Tt * Gg * Nn * 2;

#define MFMA16(a, b, c) __builtin_amdgcn_mfma_f32_16x16x32_bf16((a), (b), (c), 0, 0, 0)

__global__ void k0_prep(const float* __restrict__ Wi, const float* __restrict__ Wm,
                        const float* __restrict__ Wo,
                        bf16_t* __restrict__ WiB, bf16_t* __restrict__ WmB,
                        bf16_t* __restrict__ WoB, float* __restrict__ stats) {
    int i = blockIdx.x * blockDim.x + threadIdx.x;
    const int n1 = Hh * Nn, n2 = Hh * Hh, n3 = Nn * 2 * Hh;
    for (int idx = i; idx < n1 + n2 + n3; idx += gridDim.x * blockDim.x) {
        if (idx < n1)            WiB[idx] = (bf16_t)Wi[idx];
        else if (idx < n1 + n2)  WmB[idx - n1] = (bf16_t)Wm[idx - n1];
        else                     WoB[idx - n1 - n2] = (bf16_t)Wo[idx - n1 - n2];
    }
    if (i < 128) stats[i] = 0.f;  // fallback-path accumulator
}

// As column swizzle at 16B granularity: granule (c>>3) XOR tl=(row>>3)&7.
__device__ __forceinline__ int as_col(int row, int c) {
    return ((((c >> 3) ^ ((row >> 3) & 7)) << 3) | (c & 7));
}

// ================== kA: GEMM1 + prelu -> gi ; group mean -> gm ==================
__global__ __launch_bounds__(512, 4)
void kA_gemm1(const float* __restrict__ x, const bf16_t* __restrict__ WiB,
              const float* __restrict__ bi, const float* __restrict__ aip,
              bf16_t* __restrict__ gi, bf16_t* __restrict__ gm, int tile0) {
    __shared__ bf16_t As[128 * LDA];   // 34.8 KB
    const int tid = threadIdx.x, lane = tid & 63, w = tid >> 6;
    const int l15 = lane & 15, l4 = lane >> 4;
    const int tile = tile0 + blockIdx.x;
    const int b = tile / NTPB, t0 = (tile % NTPB) * TB;

    // stage x[b, g, n, t0:t0+16] -> As[tl*8+g][swz(n)]
    {
        const int g0 = tid >> 7, n0 = tid & 127;
        #pragma unroll
        for (int h = 0; h < 2; h++) {
            int gg = g0 + 4 * h;
            #pragma unroll
            for (int q = 0; q < 4; q++) {
                f32x4 xv = *(const f32x4*)&x[((size_t)((b * Gg + gg) * Nn + n0)) * Tt + t0 + 4 * q];
                #pragma unroll
                for (int e = 0; e < 4; e++) {
                    int row = (q * 4 + e) * Gg + gg;
                    As[row * LDA + as_col(row, n0)] = (bf16_t)xv[e];
                }
            }
        }
    }
    __syncthreads();

    const float ai = aip[0];
    const int cb = w * 48;                   // wave owns 48 cols x all 128 rows
    f32x4 acc[8][3];
    #pragma unroll
    for (int mt = 0; mt < 8; mt++)
        #pragma unroll
        for (int nc = 0; nc < 3; nc++) acc[mt][nc] = f32x4{0.f, 0.f, 0.f, 0.f};
    #pragma unroll
    for (int kk = 0; kk < 4; kk++) {
        const int k0 = kk * 32 + l4 * 8;
        bf16x8 bb[3];
        #pragma unroll
        for (int nc = 0; nc < 3; nc++)
            bb[nc] = *(const bf16x8*)&WiB[(cb + nc * 16 + l15) * Nn + k0];
        #pragma unroll
        for (int mt = 0; mt < 8; mt++) {
            int row = mt * 16 + l15;
            bf16x8 a = *(const bf16x8*)&As[row * LDA + as_col(row, k0)];
            #pragma unroll
            for (int nc = 0; nc < 3; nc++) acc[mt][nc] = MFMA16(a, bb[nc], acc[mt][nc]);
        }
    }
    // epilogue: prelu -> gi (chunk-local), in-register group mean -> gm (global)
    const size_t giBase = (size_t)blockIdx.x * 128 * Hh;
    #pragma unroll
    for (int nc = 0; nc < 3; nc++) {
        int col = cb + nc * 16 + l15;
        float bv = bi[col];
        #pragma unroll
        for (int mt = 0; mt < 8; mt++) {
            float ms = 0.f;
            #pragma unroll
            for (int j = 0; j < 4; j++) {
                int row = mt * 16 + l4 * 4 + j;
                float v = acc[mt][nc][j] + bv;
                v = v >= 0.f ? v : ai * v;
                gi[giBase + (size_t)row * Hh + col] = (bf16_t)v;
                ms += v;
            }
            ms += __shfl_xor(ms, 16, 64);    // l4 0<->1, 2<->3: full 8-g sum
            if ((l4 & 1) == 0) {
                int tl = mt * 2 + (l4 >> 1);
                gm[((size_t)tile * TB + tl) * Hh + col] = (bf16_t)(0.125f * ms);
            }
        }
    }
}

// ================== kB: gm -> GEMM2(prelu) -> GEMM3 -> v ==================
__global__ __launch_bounds__(256, 2)
void kB_mid(const bf16_t* __restrict__ gm, const bf16_t* __restrict__ WmB,
            const float* __restrict__ bm, const float* __restrict__ amp,
            const bf16_t* __restrict__ WoB, float* __restrict__ v,
            int tile0, int ntilesC) {
    __shared__ bf16_t MmS[4][16 * LDMM];    // 50 KB, per-wave private
    const int tid = threadIdx.x, lane = tid & 63, w = tid >> 6;
    const int l15 = lane & 15, l4 = lane >> 4;
    const int tileL = blockIdx.x * 4 + w;
    if (tileL >= ntilesC) return;           // no barriers in this kernel
    const int row0 = (tile0 + tileL) * TB;  // global (b,t) row
    bf16_t* Mm = MmS[w];

    // GEMM2: [16][384] = prelu(gm @ WmB^T + bm), K=384
    f32x4 acc2[24];
    #pragma unroll
    for (int nc = 0; nc < 24; nc++) acc2[nc] = f32x4{0.f, 0.f, 0.f, 0.f};
    #pragma unroll
    for (int ks = 0; ks < 12; ks++) {
        const int k0 = ks * 32 + l4 * 8;
        bf16x8 a = *(const bf16x8*)&gm[((size_t)row0 + l15) * Hh + k0];
        #pragma unroll
        for (int nc = 0; nc < 24; nc++) {
            bf16x8 bb = *(const bf16x8*)&WmB[(nc * 16 + l15) * Hh + k0];
            acc2[nc] = MFMA16(a, bb, acc2[nc]);
        }
    }
    const float am = amp[0];
    #pragma unroll
    for (int nc = 0; nc < 24; nc++) {
        int col = nc * 16 + l15;
        float bv = bm[col];
        #pragma unroll
        for (int j = 0; j < 4; j++) {
            float vv = acc2[nc][j] + bv;
            vv = vv >= 0.f ? vv : am * vv;
            Mm[(l4 * 4 + j) * LDMM + col] = (bf16_t)vv;   // within-wave: waitcnt only
        }
    }
    // GEMM3: v[16][128] = Mm @ Wo2^T, K=384
    f32x4 acc3[8];
    #pragma unroll
    for (int nc = 0; nc < 8; nc++) acc3[nc] = f32x4{0.f, 0.f, 0.f, 0.f};
    #pragma unroll
    for (int ks = 0; ks < 12; ks++) {
        const int k0 = ks * 32 + l4 * 8;
        bf16x8 a = *(const bf16x8*)&Mm[l15 * LDMM + k0];
        #pragma unroll
        for (int nc = 0; nc < 8; nc++) {
            bf16x8 bb = *(const bf16x8*)&WoB[(nc * 16 + l15) * 768 + 384 + k0];
            acc3[nc] = MFMA16(a, bb, acc3[nc]);
        }
    }
    #pragma unroll
    for (int nc = 0; nc < 8; nc++) {
        int col = nc * 16 + l15;
        #pragma unroll
        for (int j = 0; j < 4; j++)
            v[((size_t)row0 + l4 * 4 + j) * Nn + col] = acc3[nc][j];
    }
}

// ========= kC: go = prelu(gi @ Wo1^T + v + bo); per-wave LN partials =========
__global__ __launch_bounds__(256, 3)
void kC_gemm4(const bf16_t* __restrict__ gi, const float* __restrict__ v,
              const bf16_t* __restrict__ WoB, const float* __restrict__ bo,
              const float* __restrict__ aop, bf16_t* __restrict__ go,
              float* __restrict__ part, int tile0) {
    const int tid = threadIdx.x, lane = tid & 63, w = tid >> 6;
    const int l15 = lane & 15, l4 = lane >> 4;
    const int tile = tile0 + blockIdx.x;            // block = 128 rows; wave = 32
    const size_t rL0 = (size_t)blockIdx.x * 128 + w * 32;  // gi chunk-local
    const size_t Rg0 = (size_t)tile * 128 + w * 32;        // global row

    f32x4 acc[2][8];
    #pragma unroll
    for (int mt = 0; mt < 2; mt++)
        #pragma unroll
        for (int nc = 0; nc < 8; nc++) acc[mt][nc] = f32x4{0.f, 0.f, 0.f, 0.f};
    #pragma unroll
    for (int ks = 0; ks < 12; ks++) {
        const int k0 = ks * 32 + l4 * 8;
        bf16x8 bb[8];
        #pragma unroll
        for (int nc = 0; nc < 8; nc++)
            bb[nc] = *(const bf16x8*)&WoB[(nc * 16 + l15) * 768 + k0];
        #pragma unroll
        for (int mt = 0; mt < 2; mt++) {
            bf16x8 a = *(const bf16x8*)&gi[(rL0 + mt * 16 + l15) * Hh + k0];
            #pragma unroll
            for (int nc = 0; nc < 8; nc++) acc[mt][nc] = MFMA16(a, bb[nc], acc[mt][nc]);
        }
    }
    const float ao = aop[0];
    float gsum[4] = {0.f, 0.f, 0.f, 0.f};
    float gss[4]  = {0.f, 0.f, 0.f, 0.f};
    #pragma unroll
    for (int nc = 0; nc < 8; nc++) {
        int col = nc * 16 + l15;
        float bv = bo[col];
        #pragma unroll
        for (int mt = 0; mt < 2; mt++) {
            #pragma unroll
            for (int j = 0; j < 4; j++) {
                size_t Rg = Rg0 + mt * 16 + l4 * 4 + j;
                float val = acc[mt][nc][j] + v[(Rg >> 3) * Nn + col] + bv;
                val = val >= 0.f ? val : ao * val;
                go[Rg * Nn + col] = (bf16_t)val;
                gsum[j] += val;
                gss[j] += val * val;
            }
        }
    }
    #pragma unroll
    for (int j = 0; j < 4; j++) {
        float s = gsum[j], q = gss[j];
        #pragma unroll
        for (int off = 1; off < 16; off <<= 1) {
            s += __shfl_xor(s, off, 64);
            q += __shfl_xor(q, off, 64);
        }
        s += __shfl_xor(s, 32, 64);   // combine l4 0<->2, 1<->3 (same g)
        q += __shfl_xor(q, 32, 64);
        if (l15 == 0 && l4 < 2) {
            int g = l4 * 4 + j;
            part[((size_t)tile * 4 + w) * 16 + g * 2 + 0] = s;
            part[((size_t)tile * 4 + w) * 16 + g * 2 + 1] = q;
        }
    }
}

// reduce part[6000][16] -> mr[32][2]
__global__ __launch_bounds__(1024)
void k_final_split(const float* __restrict__ part, float* __restrict__ mr) {
    __shared__ float red[64][17];
    const int tid = threadIdx.x, key = tid & 63, chunk = tid >> 6;
    const int bb = key >> 4;
    const int t0 = chunk * 94;
    const int cnt = min(94, 1500 - t0);
    float s = 0.f;
    for (int i = 0; i < cnt; i++)
        s += part[(size_t)(bb * 1500 + t0 + i) * 16 + (key & 15)];
    red[key][chunk] = s;
    __syncthreads();
    if (tid < 64) {
        float tot = 0.f;
        #pragma unroll
        for (int ch = 0; ch < 16; ch++) tot += red[tid][ch];
        red[tid][16] = tot;
    }
    __syncthreads();
    if (tid < 32) {
        int b2 = tid >> 3, g2 = tid & 7;
        float s0 = red[b2 * 16 + g2 * 2][16];
        float s1 = red[b2 * 16 + g2 * 2 + 1][16];
        const float cntf = (float)Nn * (float)Tt;
        float mean = s0 / cntf;
        float var = s1 / cntf - mean * mean;
        mr[tid * 2] = mean;
        mr[tid * 2 + 1] = rsqrtf(var + 1e-8f);
    }
}

__global__ __launch_bounds__(256)
void k_apply(const float* __restrict__ x, const bf16_t* __restrict__ go,
             const float* __restrict__ mr, const float* __restrict__ gamma,
             const float* __restrict__ beta, float* __restrict__ out) {
    __shared__ float tr[32][65];
    int bid = blockIdx.x;
    const int tt = bid % 94; bid /= 94;
    const int nn = bid & 3;  bid >>= 2;
    const int g = bid & 7;
    const int b = bid >> 3;
    const int t0 = tt * 64, n0 = nn * 32;
    const int tid = threadIdx.x;
    const float mean = mr[(b * 8 + g) * 2], rstd = mr[(b * 8 + g) * 2 + 1];

    for (int idx = tid; idx < 2048; idx += 256) {
        int nl = idx & 31, tl = idx >> 5;
        int t = t0 + tl;
        float v = 0.f;
        if (t < Tt) v = (float)go[((size_t)((b * Tt + t) * Gg + g)) * Nn + n0 + nl];
        tr[nl][tl] = v;
    }
    __syncthreads();
    for (int idx = tid; idx < 2048; idx += 256) {
        int tl = idx & 63, nl = idx >> 6;
        int t = t0 + tl;
        if (t < Tt) {
            int n = n0 + nl;
            size_t a = ((size_t)((b * Gg + g) * Nn + n)) * Tt + t;
            out[a] = x[a] + gamma[n] * (tr[nl][tl] - mean) * rstd + beta[n];
        }
    }
}

// ================== fallback: R2 fused kernel (proven, ~222us) ==================
static constexpr int FB_LDA = 136, FB_LDG = 392, FB_LDSM = 392, FB_LDV = 132;
static constexpr int FB_SM_SM = 0, FB_SM_MM = 12544, FB_SM_VV = 25088,
                     FB_SM_GI = 34816, FB_SM_STT = 135168, FB_SMEM = 135232;

__global__ __launch_bounds__(512, 2)
void k1_fused_fb(const float* __restrict__ x,
                 const bf16_t* __restrict__ WiB, const float* __restrict__ bi, const float* __restrict__ aip,
                 const bf16_t* __restrict__ WmB, const float* __restrict__ bm, const float* __restrict__ amp,
                 const bf16_t* __restrict__ WoB, const float* __restrict__ bo, const float* __restrict__ aop,
                 bf16_t* __restrict__ go, float* __restrict__ stats) {
    extern __shared__ char smem[];
    bf16_t* As = (bf16_t*)(smem);
    bf16_t* Sm = (bf16_t*)(smem + FB_SM_SM);
    bf16_t* Mm = (bf16_t*)(smem + FB_SM_MM);
    float*  Vv = (float*)(smem + FB_SM_VV);
    bf16_t* Gi = (bf16_t*)(smem + FB_SM_GI);
    float*  st = (float*)(smem + FB_SM_STT);
    const int tid = threadIdx.x, lane = tid & 63, w = tid >> 6;
    const int l15 = lane & 15, l4 = lane >> 4, mh = w >> 2, ws4 = w & 3;
    const int b = blockIdx.x / NTPB, t0 = (blockIdx.x % NTPB) * TB;
    if (tid < 16) st[tid] = 0.f;
    for (int idx = tid; idx < 128 * Nn; idx += 512) {
        int tl = idx & 15, gn = idx >> 4, g = gn >> 7, n = gn & 127;
        float v = x[((size_t)((b * Gg + g) * Nn + n)) * Tt + t0 + tl];
        int row = tl * Gg + g;
        As[row * FB_LDA + as_col(row, n)] = (bf16_t)v;
    }
    __syncthreads();
    const float ai = aip[0], am = amp[0], ao = aop[0];
    {
        const int cb = ws4 * 96;
        f32x4 acc[4][6];
        #pragma unroll
        for (int mt = 0; mt < 4; mt++)
            #pragma unroll
            for (int ni = 0; ni < 6; ni++) acc[mt][ni] = f32x4{0.f, 0.f, 0.f, 0.f};
        #pragma unroll
        for (int kk = 0; kk < 4; kk++) {
            const int k0 = kk * 32 + l4 * 8;
            bf16x8 a[4], bb[6];
            #pragma unroll
            for (int ni = 0; ni < 6; ni++)
                bb[ni] = *(const bf16x8*)&WiB[(cb + ni * 16 + l15) * Nn + k0];
            #pragma unroll
            for (int mt = 0; mt < 4; mt++) {
                int row = mh * 64 + mt * 16 + l15;
                a[mt] = *(const bf16x8*)&As[row * FB_LDA + as_col(row, k0)];
            }
            #pragma unroll
            for (int mt = 0; mt < 4; mt++)
                #pragma unroll
                for (int ni = 0; ni < 6; ni++)
                    acc[mt][ni] = MFMA16(a[mt], bb[ni], acc[mt][ni]);
        }
        #pragma unroll
        for (int ni = 0; ni < 6; ni++) {
            int col = cb + ni * 16 + l15;
            float bv = bi[col];
            #pragma unroll
            for (int mt = 0; mt < 4; mt++)
                #pragma unroll
                for (int j = 0; j < 4; j++) {
                    int row = mh * 64 + mt * 16 + l4 * 4 + j;
                    float v = acc[mt][ni][j] + bv;
                    v = v >= 0.f ? v : ai * v;
                    Gi[row * FB_LDG + col] = (bf16_t)v;
                }
        }
    }
    __syncthreads();
    for (int idx = tid; idx < TB * (Hh / 8); idx += 512) {
        int tl = idx / (Hh / 8), h0 = (idx - tl * (Hh / 8)) * 8;
        float s[8];
        #pragma unroll
        for (int e = 0; e < 8; e++) s[e] = 0.f;
        #pragma unroll
        for (int g = 0; g < 8; g++) {
            bf16x8 vv = *(const bf16x8*)&Gi[(tl * 8 + g) * FB_LDG + h0];
            #pragma unroll
            for (int e = 0; e < 8; e++) s[e] += (float)vv[e];
        }
        bf16x8 o;
        #pragma unroll
        for (int e = 0; e < 8; e++) o[e] = (bf16_t)(0.125f * s[e]);
        *(bf16x8*)&Sm[tl * FB_LDSM + h0] = o;
    }
    __syncthreads();
    {
        const int cb2 = w * 48;
        f32x4 acc2[3];
        #pragma unroll
        for (int ni = 0; ni < 3; ni++) acc2[ni] = f32x4{0.f, 0.f, 0.f, 0.f};
        #pragma unroll
        for (int kk = 0; kk < 12; kk++) {
            const int k0 = kk * 32 + l4 * 8;
            bf16x8 a = *(const bf16x8*)&Sm[l15 * FB_LDSM + k0];
            #pragma unroll
            for (int ni = 0; ni < 3; ni++) {
                bf16x8 bb = *(const bf16x8*)&WmB[(cb2 + ni * 16 + l15) * Hh + k0];
                acc2[ni] = MFMA16(a, bb, acc2[ni]);
            }
        }
        #pragma unroll
        for (int ni = 0; ni < 3; ni++) {
            int col = cb2 + ni * 16 + l15;
            float bv = bm[col];
            #pragma unroll
            for (int j = 0; j < 4; j++) {
                float v = acc2[ni][j] + bv;
                v = v >= 0.f ? v : am * v;
                Mm[(l4 * 4 + j) * FB_LDSM + col] = (bf16_t)v;
            }
        }
    }
    __syncthreads();
    {
        const int nblk = w * 16;
        f32x4 acc3 = f32x4{0.f, 0.f, 0.f, 0.f};
        #pragma unroll
        for (int kk = 0; kk < 12; kk++) {
            const int k0 = kk * 32 + l4 * 8;
            bf16x8 a = *(const bf16x8*)&Mm[l15 * FB_LDSM + k0];
            bf16x8 bb = *(const bf16x8*)&WoB[(nblk + l15) * 768 + 384 + k0];
            acc3 = MFMA16(a, bb, acc3);
        }
        #pragma unroll
        for (int j = 0; j < 4; j++) Vv[(l4 * 4 + j) * FB_LDV + nblk + l15] = acc3[j];
    }
    __syncthreads();
    {
        const int cb4 = ws4 * 32;
        f32x4 acc4[4][2];
        #pragma unroll
        for (int mt = 0; mt < 4; mt++)
            #pragma unroll
            for (int ni = 0; ni < 2; ni++) acc4[mt][ni] = f32x4{0.f, 0.f, 0.f, 0.f};
        #pragma unroll
        for (int kk = 0; kk < 12; kk++) {
            const int k0 = kk * 32 + l4 * 8;
            bf16x8 b0 = *(const bf16x8*)&WoB[(cb4 + l15) * 768 + k0];
            bf16x8 b1 = *(const bf16x8*)&WoB[(cb4 + 16 + l15) * 768 + k0];
            bf16x8 a[4];
            #pragma unroll
            for (int mt = 0; mt < 4; mt++)
                a[mt] = *(const bf16x8*)&Gi[(mh * 64 + mt * 16 + l15) * FB_LDG + k0];
            #pragma unroll
            for (int mt = 0; mt < 4; mt++) {
                acc4[mt][0] = MFMA16(a[mt], b0, acc4[mt][0]);
                acc4[mt][1] = MFMA16(a[mt], b1, acc4[mt][1]);
            }
        }
        float gsum[4] = {0.f, 0.f, 0.f, 0.f};
        float gss[4]  = {0.f, 0.f, 0.f, 0.f};
        #pragma unroll
        for (int ni = 0; ni < 2; ni++) {
            int col = cb4 + ni * 16 + l15;
            float bv = bo[col];
            #pragma unroll
            for (int mt = 0; mt < 4; mt++)
                #pragma unroll
                for (int j = 0; j < 4; j++) {
                    int row = mh * 64 + mt * 16 + l4 * 4 + j;
                    int tl = row >> 3, g = row & 7;
                    float v = acc4[mt][ni][j] + Vv[tl * FB_LDV + col] + bv;
                    v = v >= 0.f ? v : ao * v;
                    go[((size_t)((b * Tt + t0 + tl) * Gg + g)) * Nn + col] = (bf16_t)v;
                    gsum[j] += v;
                    gss[j] += v * v;
                }
        }
        #pragma unroll
        for (int j = 0; j < 4; j++) {
            float s = gsum[j], q = gss[j];
            #pragma unroll
            for (int off = 1; off < 16; off <<= 1) {
                s += __shfl_xor(s, off, 64);
                q += __shfl_xor(q, off, 64);
            }
            if (l15 == 0) {
                int g = (l4 * 4 + j) & 7;
                atomicAdd(&st[g * 2 + 0], s);
                atomicAdd(&st[g * 2 + 1], q);
            }
        }
    }
    __syncthreads();
    if (tid < 16) atomicAdd(&stats[b * 16 + tid], st[tid]);
}

__global__ void k_final_fb(const float* __restrict__ stats, float* __restrict__ mr) {
    int i = threadIdx.x;
    if (i < 32) {
        const float cnt = (float)Nn * (float)Tt;
        float mean = stats[i * 2] / cnt;
        float var = stats[i * 2 + 1] / cnt - mean * mean;
        mr[i * 2] = mean;
        mr[i * 2 + 1] = rsqrtf(var + 1e-8f);
    }
}

extern "C" void kernel_launch(void* const* d_in, const int* in_sizes, int n_in,
                              void* d_out, int out_size, void* d_ws, size_t ws_size,
                              hipStream_t stream) {
    const float* x     = (const float*)d_in[0];
    const float* Wi    = (const float*)d_in[1];
    const float* bi    = (const float*)d_in[2];
    const float* ai    = (const float*)d_in[3];
    const float* Wm    = (const float*)d_in[4];
    const float* bm    = (const float*)d_in[5];
    const float* am    = (const float*)d_in[6];
    const float* Wo    = (const float*)d_in[7];
    const float* bo    = (const float*)d_in[8];
    const float* ao    = (const float*)d_in[9];
    const float* gamma = (const float*)d_in[10];
    const float* beta  = (const float*)d_in[11];
    float* out = (float*)d_out;
    char* ws = (char*)d_ws;

    bf16_t* WiB = (bf16_t*)(ws + OFF_WI);
    bf16_t* WmB = (bf16_t*)(ws + OFF_WM);
    bf16_t* WoB = (bf16_t*)(ws + OFF_WO);
    float*  prt = (float*)(ws + OFF_PT);     // split: part / fb: stats
    float*  mrs = (float*)(ws + OFF_MRS);

    // pick chunking by available workspace
    int nch = 0;
    if      (ws_size >= OFF_GI + GI_BYTES_FULL)     nch = 1;
    else if (ws_size >= OFF_GI + GI_BYTES_FULL / 2) nch = 2;
    else if (ws_size >= OFF_GI + GI_BYTES_FULL / 4) nch = 4;

    if (nch) {
        bf16_t* gm  = (bf16_t*)(ws + OFF_GM);
        float*  vv  = (float*)(ws + OFF_V);
        bf16_t* goB = (bf16_t*)(ws + OFF_GO);
        bf16_t* gic = (bf16_t*)(ws + OFF_GI);
        const int tpc = NTILES / nch;        // tiles per chunk (1500/…)

        k0_prep<<<dim3(512), dim3(256), 0, stream>>>(Wi, Wm, Wo, WiB, WmB, WoB, prt);
        for (int c = 0; c < nch; c++) {
            const int tile0 = c * tpc;
            kA_gemm1<<<dim3(tpc), dim3(512), 0, stream>>>(x, WiB, bi, ai, gic, gm, tile0);
            kB_mid<<<dim3((tpc + 3) / 4), dim3(256), 0, stream>>>(gm, WmB, bm, am, WoB, vv, tile0, tpc);
            kC_gemm4<<<dim3(tpc), dim3(256), 0, stream>>>(gic, vv, WoB, bo, ao, goB, prt, tile0);
        }
        k_final_split<<<dim3(1), dim3(1024), 0, stream>>>(prt, mrs);
        k_apply<<<dim3(Bq * Gg * 4 * 94), dim3(256), 0, stream>>>(x, goB, mrs, gamma, beta, out);
    } else if (ws_size >= WS_FB) {
        bf16_t* goB = (bf16_t*)(ws + OFF_GO_FB);
        k0_prep<<<dim3(512), dim3(256), 0, stream>>>(Wi, Wm, Wo, WiB, WmB, WoB, prt);
        k1_fused_fb<<<dim3(NTILES), dim3(512), FB_SMEM, stream>>>(
            x, WiB, bi, ai, WmB, bm, am, WoB, bo, ao, goB, prt);
        k_final_fb<<<dim3(1), dim3(64), 0, stream>>>(prt, mrs);
        k_apply<<<dim3(Bq * Gg * 4 * 94), dim3(256), 0, stream>>>(x, goB, mrs, gamma, beta, out);
    }
}

// Round 6
// 294.542 us; speedup vs baseline: 2.2951x; 1.7187x over previous
//
#include <hip/hip_runtime.h>

typedef __bf16 bf16_t;
typedef __bf16 bf16x8 __attribute__((ext_vector_type(8)));
typedef float f32x4 __attribute__((ext_vector_type(4)));

static constexpr int Bq = 4, Gg = 8, Nn = 128, Tt = 6000, Hh = 384;
static constexpr int TB = 16;              // t-values per tile
static constexpr int NTPB = Tt / TB;       // 375 tiles per batch
static constexpr int NTILES = Bq * NTPB;   // 1500 tiles (128 rows each)
static constexpr int LDA = 136;            // As row stride (bf16): 68 words, %32=4
static constexpr int LDG = 392;            // Gi row stride: 196 words, %32=4
static constexpr int LDSM = 392;           // Sm/Mm row stride
static constexpr int LDV = 132;            // Vv row stride (f32): %32=4

// workspace layout (bytes)
static constexpr size_t OFF_WI  = 0;                                    // 384x128 bf16
static constexpr size_t OFF_WM  = OFF_WI + (size_t)Hh * Nn * 2;         // 384x384 bf16
static constexpr size_t OFF_WO  = OFF_WM + (size_t)Hh * Hh * 2;         // 128x768 bf16
static constexpr size_t OFF_PT  = OFF_WO + (size_t)Nn * 2 * Hh * 2;     // part[12000][16] f32
static constexpr size_t OFF_MRS = OFF_PT + (size_t)NTILES * 8 * 16 * 4; // 32x2 f32
static constexpr size_t OFF_GO  = (size_t)2 << 20;                      // go bf16
static constexpr size_t WS_NEED = OFF_GO + (size_t)Bq * Tt * Gg * Nn * 2; // ~51.2 MB

// k1 LDS layout (bytes). As dead after GEMM1 -> Mm/Vv reuse its region.
static constexpr int SM_GI = 0;                    // Gi [128][392] bf16 = 100352
static constexpr int SM_SM = 100352;               // Sm [16][392] bf16 = 12544 -> 112896
static constexpr int SM_AS = 112896;               // As [128][136] bf16 = 34816 -> 147712
static constexpr int SM_MM = 112896;               // Mm [16][392] bf16 (reuses As)
static constexpr int SM_VV = 112896 + 12544;       // Vv [16][132] f32 = 8448 (reuses As)
static constexpr int SMEM_BYTES = 147712;          // 1 block/CU, 8 waves

#define MFMA16(a, b, c) __builtin_amdgcn_mfma_f32_16x16x32_bf16((a), (b), (c), 0, 0, 0)

__global__ void k0_prep(const float* __restrict__ Wi, const float* __restrict__ Wm,
                        const float* __restrict__ Wo,
                        bf16_t* __restrict__ WiB, bf16_t* __restrict__ WmB,
                        bf16_t* __restrict__ WoB) {
    int i = blockIdx.x * blockDim.x + threadIdx.x;
    const int n1 = Hh * Nn, n2 = Hh * Hh, n3 = Nn * 2 * Hh;
    for (int idx = i; idx < n1 + n2 + n3; idx += gridDim.x * blockDim.x) {
        if (idx < n1)            WiB[idx] = (bf16_t)Wi[idx];
        else if (idx < n1 + n2)  WmB[idx - n1] = (bf16_t)Wm[idx - n1];
        else                     WoB[idx - n1 - n2] = (bf16_t)Wo[idx - n1 - n2];
    }
}

// As column swizzle at 16B granularity: granule (c>>3) XOR tl, tl=(row>>3)&7.
// Applied on both write and read side (involution).
__device__ __forceinline__ int as_col(int row, int c) {
    return ((((c >> 3) ^ ((row >> 3) & 7)) << 3) | (c & 7));
}

__global__ __launch_bounds__(512, 1)
void k1_fused(const float* __restrict__ x,
              const bf16_t* __restrict__ WiB, const float* __restrict__ bi, const float* __restrict__ aip,
              const bf16_t* __restrict__ WmB, const float* __restrict__ bm, const float* __restrict__ amp,
              const bf16_t* __restrict__ WoB, const float* __restrict__ bo, const float* __restrict__ aop,
              bf16_t* __restrict__ go, float* __restrict__ part) {
    __shared__ char smem[SMEM_BYTES];
    bf16_t* Gi = (bf16_t*)(smem + SM_GI);
    bf16_t* Sm = (bf16_t*)(smem + SM_SM);
    bf16_t* As = (bf16_t*)(smem + SM_AS);
    bf16_t* Mm = (bf16_t*)(smem + SM_MM);
    float*  Vv = (float*)(smem + SM_VV);

    const int tid  = threadIdx.x;
    const int lane = tid & 63;
    const int w    = tid >> 6;       // wave 0..7
    const int l15  = lane & 15;
    const int l4   = lane >> 4;      // 0..3
    const int tile = blockIdx.x;
    const int b    = tile / NTPB, t0 = (tile % NTPB) * TB;

    // ---- stage x[b, g, n, t0:t0+16] -> As[tl*8+g][swz(n)], vectorized
    {
        const int g0 = tid >> 7, n0 = tid & 127;
        #pragma unroll
        for (int h = 0; h < 2; h++) {
            int gg = g0 + 4 * h;
            #pragma unroll
            for (int q = 0; q < 4; q++) {
                f32x4 xv = *(const f32x4*)&x[((size_t)((b * Gg + gg) * Nn + n0)) * Tt + t0 + 4 * q];
                #pragma unroll
                for (int e = 0; e < 4; e++) {
                    int row = (q * 4 + e) * Gg + gg;
                    As[row * LDA + as_col(row, n0)] = (bf16_t)xv[e];
                }
            }
        }
    }
    __syncthreads();   // As ready

    const float ai = aip[0], am = amp[0], ao = aop[0];

    // ---- GEMM1: Gi[128][384] = prelu(As @ WiB^T + bi), K=128
    // wave = 48-col slice x all 128 rows; in-register group mean -> Sm
    {
        const int cb = w * 48;
        f32x4 acc[8][3];
        #pragma unroll
        for (int mt = 0; mt < 8; mt++)
            #pragma unroll
            for (int nc = 0; nc < 3; nc++) acc[mt][nc] = f32x4{0.f, 0.f, 0.f, 0.f};
        #pragma unroll
        for (int kk = 0; kk < 4; kk++) {
            const int k0 = kk * 32 + l4 * 8;
            bf16x8 bb[3];
            #pragma unroll
            for (int nc = 0; nc < 3; nc++)
                bb[nc] = *(const bf16x8*)&WiB[(cb + nc * 16 + l15) * Nn + k0];
            #pragma unroll
            for (int mt = 0; mt < 8; mt++) {
                int row = mt * 16 + l15;
                bf16x8 a = *(const bf16x8*)&As[row * LDA + as_col(row, k0)];
                #pragma unroll
                for (int nc = 0; nc < 3; nc++) acc[mt][nc] = MFMA16(a, bb[nc], acc[mt][nc]);
            }
        }
        #pragma unroll
        for (int nc = 0; nc < 3; nc++) {
            int col = cb + nc * 16 + l15;
            float bv = bi[col];
            #pragma unroll
            for (int mt = 0; mt < 8; mt++) {
                float ms = 0.f;
                #pragma unroll
                for (int j = 0; j < 4; j++) {
                    int row = mt * 16 + l4 * 4 + j;
                    float v = acc[mt][nc][j] + bv;
                    v = v >= 0.f ? v : ai * v;
                    Gi[row * LDG + col] = (bf16_t)v;
                    ms += v;
                }
                ms += __shfl_xor(ms, 16, 64);   // l4 0<->1, 2<->3: all 8 g's
                if ((l4 & 1) == 0) {
                    int tl = mt * 2 + (l4 >> 1);
                    Sm[tl * LDSM + col] = (bf16_t)(0.125f * ms);
                }
            }
        }
    }
    __syncthreads();   // Gi + Sm ready (As dead)

    // ---- GEMM2: Mm[16][384] = prelu(Sm @ WmB^T + bm), K=384
    {
        const int cb2 = w * 48;
        f32x4 acc2[3];
        #pragma unroll
        for (int nc = 0; nc < 3; nc++) acc2[nc] = f32x4{0.f, 0.f, 0.f, 0.f};
        #pragma unroll
        for (int kk = 0; kk < 12; kk++) {
            const int k0 = kk * 32 + l4 * 8;
            bf16x8 a = *(const bf16x8*)&Sm[l15 * LDSM + k0];
            #pragma unroll
            for (int nc = 0; nc < 3; nc++) {
                bf16x8 bb = *(const bf16x8*)&WmB[(cb2 + nc * 16 + l15) * Hh + k0];
                acc2[nc] = MFMA16(a, bb, acc2[nc]);
            }
        }
        #pragma unroll
        for (int nc = 0; nc < 3; nc++) {
            int col = cb2 + nc * 16 + l15;
            float bv = bm[col];
            #pragma unroll
            for (int j = 0; j < 4; j++) {
                float v = acc2[nc][j] + bv;
                v = v >= 0.f ? v : am * v;
                Mm[(l4 * 4 + j) * LDSM + col] = (bf16_t)v;
            }
        }
    }
    __syncthreads();   // Mm ready

    // ---- GEMM3: Vv[16][128] = Mm @ Wo2^T, K=384  (then GEMM4 main covers the stall)
    {
        const int nblk = w * 16;
        f32x4 acc3 = f32x4{0.f, 0.f, 0.f, 0.f};
        #pragma unroll
        for (int kk = 0; kk < 12; kk++) {
            const int k0 = kk * 32 + l4 * 8;
            bf16x8 a = *(const bf16x8*)&Mm[l15 * LDSM + k0];
            bf16x8 bb = *(const bf16x8*)&WoB[(nblk + l15) * 768 + 384 + k0];
            acc3 = MFMA16(a, bb, acc3);
        }
        #pragma unroll
        for (int j = 0; j < 4; j++) Vv[(l4 * 4 + j) * LDV + nblk + l15] = acc3[j];
    }

    // ---- GEMM4 main: acc = Gi @ Wo1^T, K=384 (reads only Gi; overlaps Vv latency)
    const int mh = w >> 2, ws4 = w & 3;
    const int cb4 = ws4 * 32;
    f32x4 acc4[4][2];
    #pragma unroll
    for (int mt = 0; mt < 4; mt++)
        #pragma unroll
        for (int nc = 0; nc < 2; nc++) acc4[mt][nc] = f32x4{0.f, 0.f, 0.f, 0.f};
    #pragma unroll
    for (int kk = 0; kk < 12; kk++) {
        const int k0 = kk * 32 + l4 * 8;
        bf16x8 b0 = *(const bf16x8*)&WoB[(cb4 + l15) * 768 + k0];
        bf16x8 b1 = *(const bf16x8*)&WoB[(cb4 + 16 + l15) * 768 + k0];
        bf16x8 a[4];
        #pragma unroll
        for (int mt = 0; mt < 4; mt++)
            a[mt] = *(const bf16x8*)&Gi[(mh * 64 + mt * 16 + l15) * LDG + k0];
        #pragma unroll
        for (int mt = 0; mt < 4; mt++) {
            acc4[mt][0] = MFMA16(a[mt], b0, acc4[mt][0]);
            acc4[mt][1] = MFMA16(a[mt], b1, acc4[mt][1]);
        }
    }
    __syncthreads();   // Vv ready

    // ---- epilogue: go = prelu(acc4 + Vv + bo); per-wave LN partials -> part
    {
        float gsum[4] = {0.f, 0.f, 0.f, 0.f};
        float gss[4]  = {0.f, 0.f, 0.f, 0.f};
        #pragma unroll
        for (int nc = 0; nc < 2; nc++) {
            int col = cb4 + nc * 16 + l15;
            float bv = bo[col];
            #pragma unroll
            for (int mt = 0; mt < 4; mt++) {
                #pragma unroll
                for (int j = 0; j < 4; j++) {
                    int row = mh * 64 + mt * 16 + l4 * 4 + j;
                    int tl = row >> 3;
                    int g = row & 7;
                    float v = acc4[mt][nc][j] + Vv[tl * LDV + col] + bv;
                    v = v >= 0.f ? v : ao * v;
                    go[((size_t)((b * Tt + t0 + tl) * Gg + g)) * Nn + col] = (bf16_t)v;
                    gsum[j] += v;
                    gss[j] += v * v;
                }
            }
        }
        #pragma unroll
        for (int j = 0; j < 4; j++) {
            float s = gsum[j], q = gss[j];
            #pragma unroll
            for (int off = 1; off < 16; off <<= 1) {
                s += __shfl_xor(s, off, 64);
                q += __shfl_xor(q, off, 64);
            }
            s += __shfl_xor(s, 32, 64);   // l4 0<->2, 1<->3 (same g, other tl half)
            q += __shfl_xor(q, 32, 64);
            if (l15 == 0 && l4 < 2) {
                int g = l4 * 4 + j;
                part[((size_t)tile * 8 + w) * 16 + g * 2 + 0] = s;
                part[((size_t)tile * 8 + w) * 16 + g * 2 + 1] = q;
            }
        }
    }
}

// reduce part[12000][16] -> mr[32][2] (mean, rstd per (b,g))
__global__ __launch_bounds__(1024)
void k_final(const float* __restrict__ part, float* __restrict__ mr) {
    __shared__ float red[64][17];
    const int tid = threadIdx.x, key = tid & 63, chunk = tid >> 6;
    const int bb = key >> 4;                   // batch
    const int rowsPerB = NTPB * 8;             // 3000
    const int t0 = chunk * 188;
    const int cnt = min(188, rowsPerB - t0);
    float s = 0.f;
    for (int i = 0; i < cnt; i++)
        s += part[(size_t)(bb * rowsPerB + t0 + i) * 16 + (key & 15)];
    red[key][chunk] = s;
    __syncthreads();
    if (tid < 64) {
        float tot = 0.f;
        #pragma unroll
        for (int ch = 0; ch < 16; ch++) tot += red[tid][ch];
        red[tid][16] = tot;
    }
    __syncthreads();
    if (tid < 32) {
        int b2 = tid >> 3, g2 = tid & 7;
        float s0 = red[b2 * 16 + g2 * 2][16];
        float s1 = red[b2 * 16 + g2 * 2 + 1][16];
        const float cntf = (float)Nn * (float)Tt;  // 768000
        float mean = s0 / cntf;
        float var = s1 / cntf - mean * mean;
        mr[tid * 2] = mean;
        mr[tid * 2 + 1] = rsqrtf(var + 1e-8f);
    }
}

__global__ __launch_bounds__(256)
void k_apply(const float* __restrict__ x, const bf16_t* __restrict__ go,
             const float* __restrict__ mr, const float* __restrict__ gamma,
             const float* __restrict__ beta, float* __restrict__ out) {
    __shared__ float tr[32][65];
    int bid = blockIdx.x;
    const int tt = bid % 94; bid /= 94;
    const int nn = bid & 3;  bid >>= 2;
    const int g = bid & 7;
    const int b = bid >> 3;
    const int t0 = tt * 64, n0 = nn * 32;
    const int tid = threadIdx.x;
    const float mean = mr[(b * 8 + g) * 2], rstd = mr[(b * 8 + g) * 2 + 1];

    for (int idx = tid; idx < 2048; idx += 256) {
        int nl = idx & 31, tl = idx >> 5;
        int t = t0 + tl;
        float v = 0.f;
        if (t < Tt) v = (float)go[((size_t)((b * Tt + t) * Gg + g)) * Nn + n0 + nl];
        tr[nl][tl] = v;
    }
    __syncthreads();
    for (int idx = tid; idx < 2048; idx += 256) {
        int tl = idx & 63, nl = idx >> 6;
        int t = t0 + tl;
        if (t < Tt) {
            int n = n0 + nl;
            size_t a = ((size_t)((b * Gg + g) * Nn + n)) * Tt + t;
            out[a] = x[a] + gamma[n] * (tr[nl][tl] - mean) * rstd + beta[n];
        }
    }
}

extern "C" void kernel_launch(void* const* d_in, const int* in_sizes, int n_in,
                              void* d_out, int out_size, void* d_ws, size_t ws_size,
                              hipStream_t stream) {
    const float* x     = (const float*)d_in[0];
    const float* Wi    = (const float*)d_in[1];
    const float* bi    = (const float*)d_in[2];
    const float* ai    = (const float*)d_in[3];
    const float* Wm    = (const float*)d_in[4];
    const float* bm    = (const float*)d_in[5];
    const float* am    = (const float*)d_in[6];
    const float* Wo    = (const float*)d_in[7];
    const float* bo    = (const float*)d_in[8];
    const float* ao    = (const float*)d_in[9];
    const float* gamma = (const float*)d_in[10];
    const float* beta  = (const float*)d_in[11];
    float* out = (float*)d_out;
    char* ws = (char*)d_ws;

    if (ws_size < WS_NEED) return;  // ~51.2 MB scratch required

    bf16_t* WiB = (bf16_t*)(ws + OFF_WI);
    bf16_t* WmB = (bf16_t*)(ws + OFF_WM);
    bf16_t* WoB = (bf16_t*)(ws + OFF_WO);
    float*  prt = (float*)(ws + OFF_PT);
    float*  mrs = (float*)(ws + OFF_MRS);
    bf16_t* goB = (bf16_t*)(ws + OFF_GO);

    k0_prep<<<dim3(512), dim3(256), 0, stream>>>(Wi, Wm, Wo, WiB, WmB, WoB);
    k1_fused<<<dim3(NTILES), dim3(512), 0, stream>>>(
        x, WiB, bi, ai, WmB, bm, am, WoB, bo, ao, goB, prt);
    k_final<<<dim3(1), dim3(1024), 0, stream>>>(prt, mrs);
    k_apply<<<dim3(Bq * Gg * 4 * 94), dim3(256), 0, stream>>>(x, goB, mrs, gamma, beta, out);
}